// Round 5
// baseline (393.091 us; speedup 1.0000x reference)
//
#include <hip/hip_runtime.h>
#include <hip/hip_bf16.h>

// ChebyKAN: y[b,o] = sum_{i,d} T_d(tanh(x[b,i])) * W[i,o,d]
// GEMM M=16384, N=1024, K=9216 with generated A (packed-fp16 Chebyshev recurrence).
// R5: LDS chunk layout re-derived so every B ds_read_b128 has the per-lane
//     address function addr(l) = C + (l&15)*64 + ((l>>4)^((l>>1)&3))*16 --
//     the R2-measured ZERO-conflict pattern (R4's 32-row variant was 4-way).
//     (wc,nb,h) become bank-neutral constant offsets -> immediate ds offsets.
//     Schedule/recurrence/epilogue identical to R4 (verified race-free).

#define WSCALE 4096.0f
#define INV_WSCALE (1.0f/4096.0f)

typedef _Float16 f16;
typedef _Float16 f16x8 __attribute__((ext_vector_type(8)));
typedef float    f32x4 __attribute__((ext_vector_type(4)));
typedef float    f32x16 __attribute__((ext_vector_type(16)));

// ---- kernel 1: repack cc [I][O][9] f32 -> wt, 16B-chunk-permuted so that the
// GEMM's linear global_load_lds produces the conflict-free LDS layout.
// Region (d, ic, ncol) = 512 chunks of 16B (8KB). Chunk j holds, for e=0..7:
//   u=j>>7, h=(j>>6)&1, r=(j>>2)&15, s=j&3, t=s^((r>>1)&3), q=t&1, kl=t>>1
//   col o = ncol*128 + u*32 + q*16 + r,  i = ic*32 + h*16 + kl*8 + e
__global__ __launch_bounds__(256) void wt_transform(const float* __restrict__ cc,
                                                    f16* __restrict__ wt) {
  int t    = blockIdx.x * 256 + threadIdx.x;   // 294912 threads
  int j4   = t & 127;                          // 4-chunk group within region
  int grp  = t >> 7;
  int ncol = grp & 7;
  int rest = grp >> 3;
  int ic   = rest & 31;
  int d    = rest >> 5;                        // 0..8
  int u    = j4 >> 5;                          // (j>>7)
  int h    = (j4 >> 4) & 1;                    // ((j>>6)&1)
  int r    = j4 & 15;                          // ((j>>2)&15)
  int rk   = (r >> 1) & 3;
  size_t base = (size_t)(d * 32 + ic) * 32768 + (size_t)ncol * 4096 + (size_t)j4 * 32;
#pragma unroll
  for (int v = 0; v < 4; ++v) {                // s = v
    int tt = v ^ rk;
    int q  = tt & 1, kl = tt >> 1;
    int o  = ncol * 128 + u * 32 + q * 16 + r;
    int ib = ic * 32 + h * 16 + kl * 8;
    f16x8 val;
#pragma unroll
    for (int e = 0; e < 8; ++e)
      val[e] = (f16)(cc[((size_t)(ib + e) * 1024 + o) * 9 + d] * WSCALE);
    *(f16x8*)(wt + base + v * 8) = val;
  }
}

// ---- kernel 2: fused basis-gen + GEMM, 128x128 tile, 4 waves (2x2), wave 64x64
__global__ __launch_bounds__(256, 2) void cheby_gemm(const float* __restrict__ x,
                                                     const f16* __restrict__ wt,
                                                     float* __restrict__ out) {
  __shared__ f16 bbuf[9][4096];               // buffer per degree: 9 x 8KB = 72KB

  const int tid  = threadIdx.x;
  const int wid  = tid >> 6;
  const int lane = tid & 63;
  const int lr   = lane & 31;                 // row/col within 32-block
  const int lh   = lane >> 5;                 // k-subgroup select
  const int wr   = wid >> 1, wc = wid & 1;
  const int mrow = blockIdx.x >> 3;
  const int ncol = blockIdx.x & 7;            // round-robin XCD: wt slice L2-resident
  const int m0   = mrow * 128 + wr * 64;
  const int n0   = ncol * 128 + wc * 64;
  const int nc128 = ncol * 128;
  // R2-pattern conflict-free lane term (16B-chunk units), then f16 units:
  const int rbase = wc * 2048 + ((lane & 15) * 4 + ((lane >> 4) ^ ((lane >> 1) & 3))) * 8;

  auto stage = [&](int cn, int dn, int buf) {
    const f16* src = wt + ((size_t)(dn * 32 + cn) * 1024 + nc128) * 32;
    __builtin_amdgcn_global_load_lds(
        (const __attribute__((address_space(1))) unsigned*)(src + tid * 8),
        (__attribute__((address_space(3))) unsigned*)(&bbuf[buf][wid * 512]),
        16, 0, 0);
    __builtin_amdgcn_global_load_lds(
        (const __attribute__((address_space(1))) unsigned*)(src + 2048 + tid * 8),
        (__attribute__((address_space(3))) unsigned*)(&bbuf[buf][wid * 512 + 2048]),
        16, 0, 0);
  };
  auto stage3 = [&](int cn, int dn0, int b0) {
    stage(cn, dn0, b0); stage(cn, dn0 + 1, b0 + 1); stage(cn, dn0 + 2, b0 + 2);
  };

  f32x16 acc[2][2];
#pragma unroll
  for (int a = 0; a < 2; ++a)
#pragma unroll
    for (int b = 0; b < 2; ++b)
#pragma unroll
      for (int j = 0; j < 16; ++j) acc[a][b][j] = 0.f;

  const f16x8 ones  = {(f16)1,(f16)1,(f16)1,(f16)1,(f16)1,(f16)1,(f16)1,(f16)1};
  const f16x8 half8 = {(f16)0.5f,(f16)0.5f,(f16)0.5f,(f16)0.5f,
                       (f16)0.5f,(f16)0.5f,(f16)0.5f,(f16)0.5f};
  f16x8 Tm1[2][2], Tm2[2][2], t2v[2][2], t2n[2][2];
  f32x4 xf[2][2][2];

  auto loadx = [&](int cn) {   // 8 VMEM instrs
#pragma unroll
    for (int mb = 0; mb < 2; ++mb)
#pragma unroll
      for (int h = 0; h < 2; ++h) {
        const float* p = x + (size_t)(m0 + mb * 32 + lr) * 1024 + cn * 32 + h * 16 + lh * 8;
        xf[mb][h][0] = *(const f32x4*)p;
        xf[mb][h][1] = *(const f32x4*)(p + 4);
      }
  };
  auto dotanh = [&]() {        // xf -> t2n = 2*tanh(x) (f16, exact x2)
#pragma unroll
    for (int mb = 0; mb < 2; ++mb)
#pragma unroll
      for (int h = 0; h < 2; ++h) {
        f16x8 tv;
#pragma unroll
        for (int e = 0; e < 8; ++e) {
          float xx = (e < 4) ? xf[mb][h][0][e] : xf[mb][h][1][e - 4];
          float t  = 1.f - 2.f * __builtin_amdgcn_rcpf(__expf(2.f * xx) + 1.f);
          tv[e] = (f16)t;
        }
        t2n[mb][h] = tv + tv;
      }
  };

// one degree: recurrence -> A frags, read B frags from bbuf[D], 8 MFMAs
#define DO_DEG(D)                                                              \
  {                                                                            \
    f16x8 af[2][2];                                                            \
    if ((D) == 0) {                                                            \
      _Pragma("unroll") for (int mb = 0; mb < 2; ++mb)                         \
        _Pragma("unroll") for (int h = 0; h < 2; ++h) af[mb][h] = ones;        \
    } else if ((D) == 1) {                                                     \
      _Pragma("unroll") for (int mb = 0; mb < 2; ++mb)                         \
        _Pragma("unroll") for (int h = 0; h < 2; ++h) {                        \
          f16x8 t1 = t2v[mb][h] * half8;                                       \
          Tm1[mb][h] = t1; Tm2[mb][h] = ones; af[mb][h] = t1;                  \
        }                                                                      \
    } else {                                                                   \
      _Pragma("unroll") for (int mb = 0; mb < 2; ++mb)                         \
        _Pragma("unroll") for (int h = 0; h < 2; ++h) {                        \
          f16x8 tn = __builtin_elementwise_fma(t2v[mb][h], Tm1[mb][h], -Tm2[mb][h]); \
          Tm2[mb][h] = Tm1[mb][h]; Tm1[mb][h] = tn; af[mb][h] = tn;            \
        }                                                                      \
    }                                                                          \
    const f16* bb = &bbuf[(D)][0];                                             \
    f16x8 bf[2][2];                                                            \
    _Pragma("unroll") for (int nb = 0; nb < 2; ++nb)                           \
      _Pragma("unroll") for (int h = 0; h < 2; ++h)                            \
        bf[nb][h] = *(const f16x8*)&bb[rbase + nb * 1024 + h * 512];           \
    __builtin_amdgcn_s_setprio(1);                                             \
    _Pragma("unroll") for (int mb = 0; mb < 2; ++mb)                           \
      _Pragma("unroll") for (int nb = 0; nb < 2; ++nb) {                       \
        acc[mb][nb] = __builtin_amdgcn_mfma_f32_32x32x16_f16(af[mb][0], bf[nb][0], \
                                                             acc[mb][nb], 0, 0, 0); \
        acc[mb][nb] = __builtin_amdgcn_mfma_f32_32x32x16_f16(af[mb][1], bf[nb][1], \
                                                             acc[mb][nb], 0, 0, 0); \
      }                                                                        \
    __builtin_amdgcn_s_setprio(0);                                             \
  }

  // prologue: stage chunk0 deg 0-2 + deg 3-5, load+tanh chunk0 x
  stage3(0, 0, 0);
  stage3(0, 3, 3);
  loadx(0);
  dotanh();

  for (int c = 0; c < 32; ++c) {
    const bool lastc = (c == 31);

    // ---- phase q0: degrees 0,1,2 (bufs 0-2; staged 2 phases ago)
    asm volatile("s_waitcnt vmcnt(6)" ::: "memory");
    __builtin_amdgcn_s_barrier();
    stage3(c, 6, 6);                        // deg 6-8 chunk c -> bufs 6-8
#pragma unroll
    for (int mb = 0; mb < 2; ++mb)
#pragma unroll
      for (int h = 0; h < 2; ++h) t2v[mb][h] = t2n[mb][h];  // adopt chunk c tanh
    DO_DEG(0) DO_DEG(1) DO_DEG(2)

    // ---- phase q1: degrees 3,4,5 (bufs 3-5)
    asm volatile("s_waitcnt vmcnt(6)" ::: "memory");
    __builtin_amdgcn_s_barrier();
    if (!lastc) {
      stage3(c + 1, 0, 0);                  // deg 0-2 chunk c+1 -> bufs 0-2
      loadx(c + 1);                         // 8 VMEM, tanh'd next phase
    }
    DO_DEG(3) DO_DEG(4) DO_DEG(5)

    // ---- phase q2: degrees 6,7,8 (bufs 6-8)
    if (lastc) asm volatile("s_waitcnt vmcnt(0)" ::: "memory");
    else       asm volatile("s_waitcnt vmcnt(14)" ::: "memory");
    __builtin_amdgcn_s_barrier();
    if (!lastc) {
      stage3(c + 1, 3, 3);                  // deg 3-5 chunk c+1 -> bufs 3-5
      dotanh();                             // chunk c+1 seed
    }
    DO_DEG(6) DO_DEG(7) DO_DEG(8)
  }
#undef DO_DEG

  // epilogue: 32x32 C/D map: col = lane&31, row = (j&3) + 8*(j>>2) + 4*(lane>>5)
#pragma unroll
  for (int mb = 0; mb < 2; ++mb)
#pragma unroll
    for (int nb = 0; nb < 2; ++nb)
#pragma unroll
      for (int j = 0; j < 16; ++j) {
        int row = m0 + mb * 32 + 4 * lh + (j & 3) + 8 * (j >> 2);
        int col = n0 + nb * 32 + lr;
        out[(size_t)row * 1024 + col] = acc[mb][nb][j] * INV_WSCALE;
      }
}

extern "C" void kernel_launch(void* const* d_in, const int* in_sizes, int n_in,
                              void* d_out, int out_size, void* d_ws, size_t ws_size,
                              hipStream_t stream) {
  const float* x  = (const float*)d_in[0];
  const float* cc = (const float*)d_in[1];
  f16*   wt  = (f16*)d_ws;                // 9*32*1024*32*2 = 18,874,368 B
  float* out = (float*)d_out;

  hipLaunchKernelGGL(wt_transform, dim3(1152), dim3(256), 0, stream, cc, wt);
  hipLaunchKernelGGL(cheby_gemm, dim3(1024), dim3(256), 0, stream, x, wt, out);
}

// Round 6
// 369.945 us; speedup vs baseline: 1.0626x; 1.0626x over previous
//
#include <hip/hip_runtime.h>
#include <hip/hip_bf16.h>

// ChebyKAN: y[b,o] = sum_{i,d} T_d(tanh(x[b,i])) * W[i,o,d]
// GEMM M=16384, N=1024, K=9216 with generated A (packed-fp16 Chebyshev recurrence).
// R6: phase body rebuilt as a single fence-free DAG: all setprio brackets
//     removed (they were scheduling fences serializing rec->read->MFMA per
//     degree); A-fragments for all 3 degrees computed up front, then three
//     {ds_read x4 -> MFMA x8} clusters the scheduler can interleave.
//     Schedule (vmcnt counts, barriers, 9 bufs) identical to R4/R5.

#define WSCALE 4096.0f
#define INV_WSCALE (1.0f/4096.0f)

typedef _Float16 f16;
typedef _Float16 f16x8 __attribute__((ext_vector_type(8)));
typedef float    f32x4 __attribute__((ext_vector_type(4)));
typedef float    f32x16 __attribute__((ext_vector_type(16)));

// ---- kernel 1: repack cc [I][O][9] f32 -> wt, 16B-chunk-permuted so that the
// GEMM's linear global_load_lds produces the conflict-free LDS layout (R5).
__global__ __launch_bounds__(256) void wt_transform(const float* __restrict__ cc,
                                                    f16* __restrict__ wt) {
  int t    = blockIdx.x * 256 + threadIdx.x;   // 294912 threads
  int j4   = t & 127;
  int grp  = t >> 7;
  int ncol = grp & 7;
  int rest = grp >> 3;
  int ic   = rest & 31;
  int d    = rest >> 5;                        // 0..8
  int u    = j4 >> 5;
  int h    = (j4 >> 4) & 1;
  int r    = j4 & 15;
  int rk   = (r >> 1) & 3;
  size_t base = (size_t)(d * 32 + ic) * 32768 + (size_t)ncol * 4096 + (size_t)j4 * 32;
#pragma unroll
  for (int v = 0; v < 4; ++v) {
    int tt = v ^ rk;
    int q  = tt & 1, kl = tt >> 1;
    int o  = ncol * 128 + u * 32 + q * 16 + r;
    int ib = ic * 32 + h * 16 + kl * 8;
    f16x8 val;
#pragma unroll
    for (int e = 0; e < 8; ++e)
      val[e] = (f16)(cc[((size_t)(ib + e) * 1024 + o) * 9 + d] * WSCALE);
    *(f16x8*)(wt + base + v * 8) = val;
  }
}

// ---- kernel 2: fused basis-gen + GEMM, 128x128 tile, 4 waves (2x2), wave 64x64
__global__ __launch_bounds__(256, 2) void cheby_gemm(const float* __restrict__ x,
                                                     const f16* __restrict__ wt,
                                                     float* __restrict__ out) {
  __shared__ f16 bbuf[9][4096];               // buffer per degree: 9 x 8KB = 72KB

  const int tid  = threadIdx.x;
  const int wid  = tid >> 6;
  const int lane = tid & 63;
  const int lr   = lane & 31;
  const int lh   = lane >> 5;
  const int wr   = wid >> 1, wc = wid & 1;
  const int mrow = blockIdx.x >> 3;
  const int ncol = blockIdx.x & 7;            // round-robin XCD: wt slice L2-resident
  const int m0   = mrow * 128 + wr * 64;
  const int n0   = ncol * 128 + wc * 64;
  const int nc128 = ncol * 128;
  // R2-pattern conflict-free lane term (f16 units):
  const int rbase = wc * 2048 + ((lane & 15) * 4 + ((lane >> 4) ^ ((lane >> 1) & 3))) * 8;

  auto stage = [&](int cn, int dn, int buf) {
    const f16* src = wt + ((size_t)(dn * 32 + cn) * 1024 + nc128) * 32;
    __builtin_amdgcn_global_load_lds(
        (const __attribute__((address_space(1))) unsigned*)(src + tid * 8),
        (__attribute__((address_space(3))) unsigned*)(&bbuf[buf][wid * 512]),
        16, 0, 0);
    __builtin_amdgcn_global_load_lds(
        (const __attribute__((address_space(1))) unsigned*)(src + 2048 + tid * 8),
        (__attribute__((address_space(3))) unsigned*)(&bbuf[buf][wid * 512 + 2048]),
        16, 0, 0);
  };
  auto stage3 = [&](int cn, int dn0, int b0) {
    stage(cn, dn0, b0); stage(cn, dn0 + 1, b0 + 1); stage(cn, dn0 + 2, b0 + 2);
  };

  f32x16 acc[2][2];
#pragma unroll
  for (int a = 0; a < 2; ++a)
#pragma unroll
    for (int b = 0; b < 2; ++b)
#pragma unroll
      for (int j = 0; j < 16; ++j) acc[a][b][j] = 0.f;

  const f16x8 ones  = {(f16)1,(f16)1,(f16)1,(f16)1,(f16)1,(f16)1,(f16)1,(f16)1};
  const f16x8 half8 = {(f16)0.5f,(f16)0.5f,(f16)0.5f,(f16)0.5f,
                       (f16)0.5f,(f16)0.5f,(f16)0.5f,(f16)0.5f};
  f16x8 Tm1[2][2], Tm2[2][2], t2v[2][2], t2n[2][2];
  f32x4 xf[2][2][2];

  auto loadx = [&](int cn) {   // 8 VMEM instrs
#pragma unroll
    for (int mb = 0; mb < 2; ++mb)
#pragma unroll
      for (int h = 0; h < 2; ++h) {
        const float* p = x + (size_t)(m0 + mb * 32 + lr) * 1024 + cn * 32 + h * 16 + lh * 8;
        xf[mb][h][0] = *(const f32x4*)p;
        xf[mb][h][1] = *(const f32x4*)(p + 4);
      }
  };
  auto dotanh = [&]() {        // xf -> t2n = 2*tanh(x) (f16, exact x2)
#pragma unroll
    for (int mb = 0; mb < 2; ++mb)
#pragma unroll
      for (int h = 0; h < 2; ++h) {
        f16x8 tv;
#pragma unroll
        for (int e = 0; e < 8; ++e) {
          float xx = (e < 4) ? xf[mb][h][0][e] : xf[mb][h][1][e - 4];
          float t  = 1.f - 2.f * __builtin_amdgcn_rcpf(__expf(2.f * xx) + 1.f);
          tv[e] = (f16)t;
        }
        t2n[mb][h] = tv + tv;
      }
  };

// rec: DST = t2v * S1 - S2 (element-wise packed f16), over [2][2] frags
#define REC(DST, S1, S2)                                                       \
  _Pragma("unroll") for (int mb = 0; mb < 2; ++mb)                             \
    _Pragma("unroll") for (int h = 0; h < 2; ++h)                              \
      DST[mb][h] = __builtin_elementwise_fma(t2v[mb][h], S1[mb][h], -S2[mb][h]);

// cluster: read B frags from bbuf[D] (immediate offsets), 8 MFMAs with AF
#define CLUSTER(AF, D)                                                         \
  {                                                                            \
    const f16* bb = &bbuf[(D)][0];                                             \
    f16x8 bf[2][2];                                                            \
    _Pragma("unroll") for (int nb = 0; nb < 2; ++nb)                           \
      _Pragma("unroll") for (int h = 0; h < 2; ++h)                            \
        bf[nb][h] = *(const f16x8*)&bb[rbase + nb * 1024 + h * 512];           \
    _Pragma("unroll") for (int mb = 0; mb < 2; ++mb)                           \
      _Pragma("unroll") for (int nb = 0; nb < 2; ++nb) {                       \
        acc[mb][nb] = __builtin_amdgcn_mfma_f32_32x32x16_f16(AF[mb][0], bf[nb][0], \
                                                             acc[mb][nb], 0, 0, 0); \
        acc[mb][nb] = __builtin_amdgcn_mfma_f32_32x32x16_f16(AF[mb][1], bf[nb][1], \
                                                             acc[mb][nb], 0, 0, 0); \
      }                                                                        \
  }

  // prologue: stage chunk0 deg 0-2 + deg 3-5, load+tanh chunk0 x
  stage3(0, 0, 0);
  stage3(0, 3, 3);
  loadx(0);
  dotanh();

  f16x8 onesA[2][2], A1[2][2], A2[2][2];
#pragma unroll
  for (int mb = 0; mb < 2; ++mb)
#pragma unroll
    for (int h = 0; h < 2; ++h) onesA[mb][h] = ones;

  for (int c = 0; c < 32; ++c) {
    const bool lastc = (c == 31);

    // ---- phase q0: degrees 0,1,2 (bufs 0-2; staged 2 phases ago)
    asm volatile("s_waitcnt vmcnt(6)" ::: "memory");
    __builtin_amdgcn_s_barrier();
    stage3(c, 6, 6);                        // deg 6-8 chunk c -> bufs 6-8
#pragma unroll
    for (int mb = 0; mb < 2; ++mb)
#pragma unroll
      for (int h = 0; h < 2; ++h) {
        t2v[mb][h] = t2n[mb][h];            // adopt chunk c tanh
        A1[mb][h]  = t2v[mb][h] * half8;    // T1 = t (exact)
      }
    REC(A2, A1, onesA)                      // T2 = 2t*T1 - 1
    CLUSTER(onesA, 0)
    CLUSTER(A1, 1)
    CLUSTER(A2, 2)
#pragma unroll
    for (int mb = 0; mb < 2; ++mb)
#pragma unroll
      for (int h = 0; h < 2; ++h) { Tm1[mb][h] = A2[mb][h]; Tm2[mb][h] = A1[mb][h]; }

    // ---- phase q1: degrees 3,4,5 (bufs 3-5)
    asm volatile("s_waitcnt vmcnt(6)" ::: "memory");
    __builtin_amdgcn_s_barrier();
    if (!lastc) {
      stage3(c + 1, 0, 0);                  // deg 0-2 chunk c+1 -> bufs 0-2
      loadx(c + 1);                         // 8 VMEM, tanh'd next phase
    }
    {
      f16x8 A3[2][2], A4[2][2], A5[2][2];
      REC(A3, Tm1, Tm2)
      REC(A4, A3, Tm1)
      REC(A5, A4, A3)
      CLUSTER(A3, 3)
      CLUSTER(A4, 4)
      CLUSTER(A5, 5)
#pragma unroll
      for (int mb = 0; mb < 2; ++mb)
#pragma unroll
        for (int h = 0; h < 2; ++h) { Tm1[mb][h] = A5[mb][h]; Tm2[mb][h] = A4[mb][h]; }
    }

    // ---- phase q2: degrees 6,7,8 (bufs 6-8)
    if (lastc) asm volatile("s_waitcnt vmcnt(0)" ::: "memory");
    else       asm volatile("s_waitcnt vmcnt(14)" ::: "memory");
    __builtin_amdgcn_s_barrier();
    if (!lastc) {
      stage3(c + 1, 3, 3);                  // deg 3-5 chunk c+1 -> bufs 3-5
      dotanh();                             // chunk c+1 seed (overlappable VALU)
    }
    {
      f16x8 A6[2][2], A7[2][2], A8[2][2];
      REC(A6, Tm1, Tm2)
      REC(A7, A6, Tm1)
      REC(A8, A7, A6)
      CLUSTER(A6, 6)
      CLUSTER(A7, 7)
      CLUSTER(A8, 8)
    }
  }
#undef REC
#undef CLUSTER

  // epilogue: 32x32 C/D map: col = lane&31, row = (j&3) + 8*(j>>2) + 4*(lane>>5)
#pragma unroll
  for (int mb = 0; mb < 2; ++mb)
#pragma unroll
    for (int nb = 0; nb < 2; ++nb)
#pragma unroll
      for (int j = 0; j < 16; ++j) {
        int row = m0 + mb * 32 + 4 * lh + (j & 3) + 8 * (j >> 2);
        int col = n0 + nb * 32 + lr;
        out[(size_t)row * 1024 + col] = acc[mb][nb][j] * INV_WSCALE;
      }
}

extern "C" void kernel_launch(void* const* d_in, const int* in_sizes, int n_in,
                              void* d_out, int out_size, void* d_ws, size_t ws_size,
                              hipStream_t stream) {
  const float* x  = (const float*)d_in[0];
  const float* cc = (const float*)d_in[1];
  f16*   wt  = (f16*)d_ws;                // 9*32*1024*32*2 = 18,874,368 B
  float* out = (float*)d_out;

  hipLaunchKernelGGL(wt_transform, dim3(1152), dim3(256), 0, stream, cc, wt);
  hipLaunchKernelGGL(cheby_gemm, dim3(1024), dim3(256), 0, stream, x, wt, out);
}

// Round 10
// 359.054 us; speedup vs baseline: 1.0948x; 1.0303x over previous
//
#include <hip/hip_runtime.h>
#include <hip/hip_bf16.h>

// ChebyKAN: y[b,o] = sum_{i,d} T_d(tanh(x[b,i])) * W[i,o,d]
// GEMM M=16384, N=1024, K=9216 with generated A (packed-fp16 Chebyshev recurrence).
// R7b: wave reshape 2x2(64x64) -> 4x1(32x128): halves per-wave A-side VALU
//     (recurrence+tanh) and kills x/tanh duplication across wc-waves; B-reads
//     double (LDS BW has headroom). tanh packs via cvt_pkrtz (fix: __fp16x2
//     union member for the builtin's return type). Same R5 wt layout, same
//     9-buf depth-2 schedule, waits: q0=10, q1=6, q2=10.

#define WSCALE 4096.0f
#define INV_WSCALE (1.0f/4096.0f)

typedef _Float16 f16;
typedef __fp16   hf2  __attribute__((ext_vector_type(2)));
typedef _Float16 f16x8 __attribute__((ext_vector_type(8)));
typedef float    f32x4 __attribute__((ext_vector_type(4)));
typedef float    f32x16 __attribute__((ext_vector_type(16)));

union F16x8u { hf2 h2[4]; f16x8 v8; };

// ---- kernel 1: repack cc [I][O][9] f32 -> wt, 16B-chunk-permuted so the
// GEMM's linear global_load_lds produces the conflict-free LDS layout (R5).
__global__ __launch_bounds__(256) void wt_transform(const float* __restrict__ cc,
                                                    f16* __restrict__ wt) {
  int t    = blockIdx.x * 256 + threadIdx.x;   // 294912 threads
  int j4   = t & 127;
  int grp  = t >> 7;
  int ncol = grp & 7;
  int rest = grp >> 3;
  int ic   = rest & 31;
  int d    = rest >> 5;                        // 0..8
  int u    = j4 >> 5;
  int h    = (j4 >> 4) & 1;
  int r    = j4 & 15;
  int rk   = (r >> 1) & 3;
  size_t base = (size_t)(d * 32 + ic) * 32768 + (size_t)ncol * 4096 + (size_t)j4 * 32;
#pragma unroll
  for (int v = 0; v < 4; ++v) {
    int tt = v ^ rk;
    int q  = tt & 1, kl = tt >> 1;
    int o  = ncol * 128 + u * 32 + q * 16 + r;
    int ib = ic * 32 + h * 16 + kl * 8;
    f16x8 val;
#pragma unroll
    for (int e = 0; e < 8; ++e)
      val[e] = (f16)(cc[((size_t)(ib + e) * 1024 + o) * 9 + d] * WSCALE);
    *(f16x8*)(wt + base + v * 8) = val;
  }
}

// ---- kernel 2: fused basis-gen + GEMM, 128x128 tile, 4 waves of 32m x 128n
__global__ __launch_bounds__(256, 2) void cheby_gemm(const float* __restrict__ x,
                                                     const f16* __restrict__ wt,
                                                     float* __restrict__ out) {
  __shared__ f16 bbuf[9][4096];               // buffer per degree: 9 x 8KB = 72KB

  const int tid  = threadIdx.x;
  const int wid  = tid >> 6;                  // wave id = m-stripe 0..3
  const int lane = tid & 63;
  const int lr   = lane & 31;                 // m-row within stripe / B col within 32
  const int lh   = lane >> 5;                 // k-subgroup select
  const int mrow = blockIdx.x >> 3;
  const int ncol = blockIdx.x & 7;            // round-robin XCD: wt slice L2-resident
  const int m0   = mrow * 128 + wid * 32;
  const int n0   = ncol * 128;
  const int nc128 = ncol * 128;
  // R2-pattern conflict-free lane term (f16 units), nb/h become imm offsets:
  const int rbase = ((lane & 15) * 4 + ((lane >> 4) ^ ((lane >> 1) & 3))) * 8;

  auto stage = [&](int cn, int dn, int buf) {
    const f16* src = wt + ((size_t)(dn * 32 + cn) * 1024 + nc128) * 32;
    __builtin_amdgcn_global_load_lds(
        (const __attribute__((address_space(1))) unsigned*)(src + tid * 8),
        (__attribute__((address_space(3))) unsigned*)(&bbuf[buf][wid * 512]),
        16, 0, 0);
    __builtin_amdgcn_global_load_lds(
        (const __attribute__((address_space(1))) unsigned*)(src + 2048 + tid * 8),
        (__attribute__((address_space(3))) unsigned*)(&bbuf[buf][wid * 512 + 2048]),
        16, 0, 0);
  };
  auto stage3 = [&](int cn, int dn0, int b0) {
    stage(cn, dn0, b0); stage(cn, dn0 + 1, b0 + 1); stage(cn, dn0 + 2, b0 + 2);
  };

  f32x16 acc[4];
#pragma unroll
  for (int b = 0; b < 4; ++b)
#pragma unroll
    for (int j = 0; j < 16; ++j) acc[b][j] = 0.f;

  const f16x8 ones  = {(f16)1,(f16)1,(f16)1,(f16)1,(f16)1,(f16)1,(f16)1,(f16)1};
  const f16x8 half8 = {(f16)0.5f,(f16)0.5f,(f16)0.5f,(f16)0.5f,
                       (f16)0.5f,(f16)0.5f,(f16)0.5f,(f16)0.5f};
  f16x8 Tm1[2], Tm2[2], t2v[2], t2n[2];
  f32x4 xf[2][2];

  auto loadx = [&](int cn) {   // 4 VMEM instrs
#pragma unroll
    for (int h = 0; h < 2; ++h) {
      const float* p = x + (size_t)(m0 + lr) * 1024 + cn * 32 + h * 16 + lh * 8;
      xf[h][0] = *(const f32x4*)p;
      xf[h][1] = *(const f32x4*)(p + 4);
    }
  };
  auto dotanh = [&]() {        // xf -> t2n = 2*tanh(x) (f16 via cvt_pkrtz)
#pragma unroll
    for (int h = 0; h < 2; ++h) {
      float tf[8];
#pragma unroll
      for (int e = 0; e < 8; ++e) {
        float xx = (e < 4) ? xf[h][0][e] : xf[h][1][e - 4];
        tf[e] = 1.f - 2.f * __builtin_amdgcn_rcpf(__expf(2.f * xx) + 1.f);
      }
      F16x8u u;
#pragma unroll
      for (int p = 0; p < 4; ++p)
        u.h2[p] = __builtin_amdgcn_cvt_pkrtz(tf[2 * p], tf[2 * p + 1]);
      t2n[h] = u.v8 + u.v8;    // exact x2
    }
  };

// rec: DST = t2v * S1 - S2 (packed f16), over [2] h-frags
#define REC(DST, S1, S2)                                                       \
  _Pragma("unroll") for (int h = 0; h < 2; ++h)                                \
    DST[h] = __builtin_elementwise_fma(t2v[h], S1[h], -S2[h]);

// cluster: read 8 B frags from bbuf[D] (imm offsets), 8 MFMAs with AF
#define CLUSTER(AF, D)                                                         \
  {                                                                            \
    const f16* bb = &bbuf[(D)][0];                                             \
    f16x8 bf[4][2];                                                            \
    _Pragma("unroll") for (int nb = 0; nb < 4; ++nb)                           \
      _Pragma("unroll") for (int h = 0; h < 2; ++h)                            \
        bf[nb][h] = *(const f16x8*)&bb[rbase + nb * 1024 + h * 512];           \
    _Pragma("unroll") for (int nb = 0; nb < 4; ++nb) {                         \
      acc[nb] = __builtin_amdgcn_mfma_f32_32x32x16_f16(AF[0], bf[nb][0],       \
                                                       acc[nb], 0, 0, 0);      \
      acc[nb] = __builtin_amdgcn_mfma_f32_32x32x16_f16(AF[1], bf[nb][1],       \
                                                       acc[nb], 0, 0, 0);      \
    }                                                                          \
  }

  // prologue: stage chunk0 deg 0-2 + deg 3-5, load+tanh chunk0 x
  stage3(0, 0, 0);
  stage3(0, 3, 3);
  loadx(0);
  dotanh();

  f16x8 onesA[2], A1[2], A2[2];
#pragma unroll
  for (int h = 0; h < 2; ++h) onesA[h] = ones;

  for (int c = 0; c < 32; ++c) {
    const bool lastc = (c == 31);

    // ---- phase q0: degrees 0,1,2 (bufs 0-2; staged at q1 of c-1)
    // in-flight at entry: stage3(c,0-2)[6], loadx(c)[4], stage3(c,3-5)[6];
    // vmcnt(10) drains the 6 oldest = stage3(c,0-2).
    asm volatile("s_waitcnt vmcnt(10)" ::: "memory");
    __builtin_amdgcn_s_barrier();
    stage3(c, 6, 6);                        // deg 6-8 chunk c -> bufs 6-8
#pragma unroll
    for (int h = 0; h < 2; ++h) {
      t2v[h] = t2n[h];                      // adopt chunk c tanh
      A1[h]  = t2v[h] * half8;              // T1 = t (exact)
    }
    REC(A2, A1, onesA)                      // T2 = 2t*T1 - 1
    CLUSTER(onesA, 0)
    CLUSTER(A1, 1)
    CLUSTER(A2, 2)
#pragma unroll
    for (int h = 0; h < 2; ++h) { Tm1[h] = A2[h]; Tm2[h] = A1[h]; }

    // ---- phase q1: degrees 3,4,5 (bufs 3-5; staged at q2 of c-1)
    // vmcnt(6) drains through stage3(c,3-5).
    asm volatile("s_waitcnt vmcnt(6)" ::: "memory");
    __builtin_amdgcn_s_barrier();
    if (!lastc) {
      stage3(c + 1, 0, 0);                  // deg 0-2 chunk c+1 -> bufs 0-2
      loadx(c + 1);                         // 4 VMEM, tanh'd at q2
    }
    {
      f16x8 A3[2], A4[2], A5[2];
      REC(A3, Tm1, Tm2)
      REC(A4, A3, Tm1)
      REC(A5, A4, A3)
      CLUSTER(A3, 3)
      CLUSTER(A4, 4)
      CLUSTER(A5, 5)
#pragma unroll
      for (int h = 0; h < 2; ++h) { Tm1[h] = A5[h]; Tm2[h] = A4[h]; }
    }

    // ---- phase q2: degrees 6,7,8 (bufs 6-8; staged at q0 of c)
    // vmcnt(10) drains the 6 oldest = stage3(c,6-8).
    if (lastc) asm volatile("s_waitcnt vmcnt(0)" ::: "memory");
    else       asm volatile("s_waitcnt vmcnt(10)" ::: "memory");
    __builtin_amdgcn_s_barrier();
    if (!lastc) {
      stage3(c + 1, 3, 3);                  // deg 3-5 chunk c+1 -> bufs 3-5
      dotanh();                             // chunk c+1 seed (overlappable VALU)
    }
    {
      f16x8 A6[2], A7[2], A8[2];
      REC(A6, Tm1, Tm2)
      REC(A7, A6, Tm1)
      REC(A8, A7, A6)
      CLUSTER(A6, 6)
      CLUSTER(A7, 7)
      CLUSTER(A8, 8)
    }
  }
#undef REC
#undef CLUSTER

  // epilogue: 32x32 C/D map: col = lane&31, row = (j&3) + 8*(j>>2) + 4*(lane>>5)
#pragma unroll
  for (int nb = 0; nb < 4; ++nb)
#pragma unroll
    for (int j = 0; j < 16; ++j) {
      int row = m0 + 4 * lh + (j & 3) + 8 * (j >> 2);
      int col = n0 + nb * 32 + lr;
      out[(size_t)row * 1024 + col] = acc[nb][j] * INV_WSCALE;
    }
}

extern "C" void kernel_launch(void* const* d_in, const int* in_sizes, int n_in,
                              void* d_out, int out_size, void* d_ws, size_t ws_size,
                              hipStream_t stream) {
  const float* x  = (const float*)d_in[0];
  const float* cc = (const float*)d_in[1];
  f16*   wt  = (f16*)d_ws;                // 9*32*1024*32*2 = 18,874,368 B
  float* out = (float*)d_out;

  hipLaunchKernelGGL(wt_transform, dim3(1152), dim3(256), 0, stream, cc, wt);
  hipLaunchKernelGGL(cheby_gemm, dim3(1024), dim3(256), 0, stream, x, wt, out);
}